// Round 8
// baseline (269.278 us; speedup 1.0000x reference)
//
#include <hip/hip_runtime.h>
#include <cstdint>
#include <cstddef>

// B=8, C=256, N=1024, T=60
// seq [B][C][N][T] fp32 (503 MB), out [B][T][T] fp32
//
// R8 = DECOMPOSITION PROBE: kA launched twice (idempotent, deterministic).
// kA_duration = total_R8 - total_R7(180.0us). All kernels byte-frozen from R7.
//
// ws layout (float offsets):
//   f1p : [8 cg][B][60][1024] partials over c-groups  -> 3,932,160  @ 0
//   f2p : [B][C][16 chunks][60] partials over n       -> 1,966,080  @ 3,932,160
//   f2  : [B][C][60]                                  ->   122,880  @ 5,898,240
//   g1  : [B][60][C]                                  ->   122,880  @ 6,021,120
//   logits: [B][60][60]                               ->    28,800  @ 6,144,000
//   l2  : [B][60][60]                                 ->    28,800  @ 6,172,800
//   stats: mean[60]@+0, rstd[60]@+64                  ->       128  @ 6,201,600

#define CSTRIDE 61440  // 1024*60 floats per c-plane

typedef float vfloat4 __attribute__((ext_vector_type(4)));

// quad-lane (xor1 + xor2) sum via DPP quad_perm — VALU only, no LDS pipe.
__device__ __forceinline__ float quad_reduce(float x) {
    int y1 = __builtin_amdgcn_update_dpp(0, __float_as_int(x), 0xB1, 0xF, 0xF, true);
    float s1 = x + __int_as_float(y1);
    int y2 = __builtin_amdgcn_update_dpp(0, __float_as_int(s1), 0x4E, 0xF, 0xF, true);
    return s1 + __int_as_float(y2);
}

// ---------------------------------------------------------------------------
// Kernel A (FROZEN from R7): 4-deep NT pipeline; DPP f2 reduce; LDS buffer;
// cross-wave reduce + flush to f2p [B][C][16][60].
// ---------------------------------------------------------------------------
__global__ __launch_bounds__(256) void kA(const float* __restrict__ seq,
                                          const float* __restrict__ w1,
                                          const float* __restrict__ w2,
                                          float* __restrict__ f1p,
                                          float* __restrict__ f2p) {
    const int blk  = blockIdx.x;            // 1024
    const int b    = blk >> 7;              // 0..7
    const int cg   = (blk >> 4) & 7;        // 0..7
    const int nc   = blk & 15;              // 0..15
    const int tid  = threadIdx.x;
    const int wv   = tid >> 6;              // 0..3
    const int lane = tid & 63;
    const int q    = lane & 3;              // n-sub
    const int r    = lane >> 2;             // t-quad; r==15 inactive
    const bool act = (r < 15);
    const int base_n = (nc << 6) + (wv << 4);
    const int c0   = cg << 5;

    __shared__ float lf2[7680];             // [cc 32][wv 4][60]

    float w2v[4];
    #pragma unroll
    for (int j = 0; j < 4; ++j) w2v[j] = w2[base_n + 4 * j + q];

    const size_t planeOff = (size_t)(b * 256 + c0) * CSTRIDE + (size_t)((base_n + q) * 60 + 4 * r);
    const float* p0 = seq + planeOff;
    const float* p1 = p0 + (size_t)CSTRIDE;
    const float* p2 = p0 + 2 * (size_t)CSTRIDE;
    const float* p3 = p0 + 3 * (size_t)CSTRIDE;

    vfloat4 P0[4], P1[4], P2[4], P3[4];
    #pragma unroll
    for (int j = 0; j < 4; ++j) {
        P0[j] = (vfloat4)(0.f);
        P1[j] = P0[j]; P2[j] = P0[j]; P3[j] = P0[j];
    }
    if (act) {
        #pragma unroll
        for (int j = 0; j < 4; ++j) P0[j] = __builtin_nontemporal_load((const vfloat4*)(p0 + j * 240));
        #pragma unroll
        for (int j = 0; j < 4; ++j) P1[j] = __builtin_nontemporal_load((const vfloat4*)(p1 + j * 240));
        #pragma unroll
        for (int j = 0; j < 4; ++j) P2[j] = __builtin_nontemporal_load((const vfloat4*)(p2 + j * 240));
        #pragma unroll
        for (int j = 0; j < 4; ++j) P3[j] = __builtin_nontemporal_load((const vfloat4*)(p3 + j * 240));
    }
    p0 += 4 * (size_t)CSTRIDE;
    p1 += 4 * (size_t)CSTRIDE;
    p2 += 4 * (size_t)CSTRIDE;
    p3 += 4 * (size_t)CSTRIDE;

    vfloat4 acc[4];
    #pragma unroll
    for (int j = 0; j < 4; ++j) acc[j] = (vfloat4)(0.f);

#define KA_STEP(P, S, PP)                                                               \
    {                                                                                   \
        const int cc = (ii << 2) + (S);                                                 \
        const float wc = w1[c0 + cc];                                                   \
        _Pragma("unroll")                                                               \
        for (int j = 0; j < 4; ++j) acc[j] += wc * P[j];                                \
        vfloat4 f2v = w2v[0]*P[0] + w2v[1]*P[1] + w2v[2]*P[2] + w2v[3]*P[3];            \
        if (pref) {                                                                     \
            _Pragma("unroll")                                                           \
            for (int j = 0; j < 4; ++j)                                                 \
                P[j] = __builtin_nontemporal_load((const vfloat4*)((PP) + j * 240));    \
        }                                                                               \
        f2v.x = quad_reduce(f2v.x);                                                     \
        f2v.y = quad_reduce(f2v.y);                                                     \
        f2v.z = quad_reduce(f2v.z);                                                     \
        f2v.w = quad_reduce(f2v.w);                                                     \
        if (act && q == 0) {                                                            \
            *(vfloat4*)(&lf2[(cc * 4 + wv) * 60 + 4 * r]) = f2v;                        \
        }                                                                               \
    }

    for (int ii = 0; ii < 8; ++ii) {
        const bool pref = act && (ii < 7);
        KA_STEP(P0, 0, p0)
        KA_STEP(P1, 1, p1)
        KA_STEP(P2, 2, p2)
        KA_STEP(P3, 3, p3)
        p0 += 4 * (size_t)CSTRIDE;
        p1 += 4 * (size_t)CSTRIDE;
        p2 += 4 * (size_t)CSTRIDE;
        p3 += 4 * (size_t)CSTRIDE;
    }
#undef KA_STEP

    if (act) {
        float* dst = f1p + ((size_t)((cg * 8 + b) * 60 + 4 * r)) * 1024 + base_n + q;
        #pragma unroll
        for (int j = 0; j < 4; ++j) {
            dst[0 * 1024 + 4 * j] = acc[j].x;
            dst[1 * 1024 + 4 * j] = acc[j].y;
            dst[2 * 1024 + 4 * j] = acc[j].z;
            dst[3 * 1024 + 4 * j] = acc[j].w;
        }
    }

    __syncthreads();
    #pragma unroll
    for (int k = 0; k < 2; ++k) {
        const int id4 = tid + k * 256;
        if (id4 < 480) {
            const int cc = id4 / 15;
            const int p  = id4 - cc * 15;
            vfloat4 s = (vfloat4)(0.f);
            #pragma unroll
            for (int w = 0; w < 4; ++w)
                s += *(const vfloat4*)(&lf2[(cc * 4 + w) * 60 + 4 * p]);
            *(vfloat4*)(f2p + ((size_t)(b * 256 + c0 + cc) * 16 + nc) * 60 + 4 * p) = s;
        }
    }
}

// ---------------------------------------------------------------------------
// Kernel R (FROZEN from R7)
// ---------------------------------------------------------------------------
__global__ __launch_bounds__(256) void kR(const float* __restrict__ f2p,
                                          float* __restrict__ f2) {
    const int tid = threadIdx.x;
    const int row = blockIdx.x * 4 + (tid >> 6);   // (b*256+c)
    const int t   = tid & 63;
    if (t >= 60) return;
    const float* src = f2p + (size_t)row * 960 + t;
    float s = 0.f;
    #pragma unroll
    for (int k = 0; k < 16; ++k) s += src[k * 60];
    f2[(size_t)row * 60 + t] = s;
}

// ---------------------------------------------------------------------------
// Kernel C (FROZEN from R7)
// ---------------------------------------------------------------------------
__global__ __launch_bounds__(256) void kC(const float* __restrict__ f1p,
                                          const float* __restrict__ w,
                                          float* __restrict__ g1) {
    const int b  = blockIdx.x / 30;
    const int tg = blockIdx.x % 30;
    const int c  = threadIdx.x;
    __shared__ float fl[2048];

    #pragma unroll
    for (int k = 0; k < 2; ++k) {
        const int idx  = c + k * 256;
        const int row  = idx >> 8;
        const int col4 = idx & 255;
        const int t    = tg * 2 + row;
        vfloat4 s = (vfloat4)(0.f);
        #pragma unroll
        for (int g = 0; g < 8; ++g)
            s += *(const vfloat4*)(f1p + ((size_t)((g * 8 + b) * 60 + t)) * 1024 + 4 * col4);
        *(vfloat4*)(&fl[row * 1024 + 4 * col4]) = s;
    }
    __syncthreads();

    float a0 = 0.f, a1 = 0.f;
    #pragma unroll 4
    for (int n = 0; n < 1024; ++n) {
        const float wv = w[n * 256 + c];
        a0 += fl[n] * wv;
        a1 += fl[1024 + n] * wv;
    }
    float* dst = g1 + ((size_t)b * 60 + (size_t)(tg * 2)) * 256 + c;
    dst[0]   = a0;
    dst[256] = a1;
}

// ---------------------------------------------------------------------------
// Kernel D (FROZEN from R3)
// ---------------------------------------------------------------------------
__global__ __launch_bounds__(256) void kD(const float* __restrict__ g1,
                                          const float* __restrict__ f2,
                                          const float* __restrict__ bmat,
                                          float* __restrict__ logits) {
    const int bt = blockIdx.x;
    const int b  = bt / 60;
    const int t  = bt % 60;
    const int tid = threadIdx.x;
    const int cq = tid >> 6;
    const int s  = tid & 63;

    __shared__ float f2s[15364];
    __shared__ float g1r[256];
    __shared__ float red[256];

    const float* fsrc = f2 + (size_t)b * 15360;
    #pragma unroll
    for (int k = 0; k < 15; ++k) {
        const int idx = tid + k * 256;
        *(float4*)(&f2s[4 * idx]) = *(const float4*)(fsrc + 4 * idx);
    }
    if (tid < 64) {
        *(float4*)(&g1r[4 * tid]) = *(const float4*)(g1 + (size_t)bt * 256 + 4 * tid);
    }
    __syncthreads();

    float acc = 0.f;
    #pragma unroll 8
    for (int cc = 0; cc < 64; ++cc) {
        const int c = cq * 64 + cc;
        acc += g1r[c] * f2s[c * 60 + s];
    }
    red[tid] = acc;
    __syncthreads();
    if (tid < 60) {
        const float x = red[tid] + red[64 + tid] + red[128 + tid] + red[192 + tid]
                      + bmat[t * 60 + tid];
        logits[(size_t)bt * 60 + tid] = 1.f / (1.f + __expf(-x));
    }
}

// ---------------------------------------------------------------------------
// Kernel E (FROZEN from R3)
// ---------------------------------------------------------------------------
__global__ __launch_bounds__(256) void kE(const float* __restrict__ v,
                                          const float* __restrict__ logits,
                                          float* __restrict__ l2) {
    const int bi = blockIdx.x;
    const int b  = bi / 60;
    const int i  = bi % 60;
    const int tid = threadIdx.x;

    __shared__ float L[3600];
    const float* src = logits + (size_t)b * 3600;
    #pragma unroll
    for (int k = 0; k < 3; ++k) {
        const int idx = tid + k * 256;
        *(float4*)(&L[4 * idx]) = *(const float4*)(src + 4 * idx);
    }
    if (tid < 132) {
        const int idx = tid + 768;
        *(float4*)(&L[4 * idx]) = *(const float4*)(src + 4 * idx);
    }
    __syncthreads();

    if (tid < 60) {
        float acc = 0.f;
        #pragma unroll 4
        for (int j = 0; j < 60; ++j) acc += v[i * 60 + j] * L[j * 60 + tid];
        l2[(size_t)bi * 60 + tid] = acc;
    }
}

// ---------------------------------------------------------------------------
// Kernel F (FROZEN from R3)
// ---------------------------------------------------------------------------
__global__ __launch_bounds__(64) void kF(const float* __restrict__ l2,
                                         float* __restrict__ stats) {
    const int t = blockIdx.x;
    const int k = threadIdx.x;
    float s = 0.f, ss = 0.f;
    #pragma unroll
    for (int m = 0; m < 8; ++m) {
        const int idx = k + 64 * m;
        if (idx < 480) {
            const float x = l2[(size_t)idx * 60 + t];
            s  += x;
            ss += x * x;
        }
    }
    #pragma unroll
    for (int o = 32; o > 0; o >>= 1) { s += __shfl_xor(s, o); ss += __shfl_xor(ss, o); }
    if (k == 0) {
        const float m   = s * (1.f / 480.f);
        const float var = ss * (1.f / 480.f) - m * m;
        stats[t]      = m;
        stats[64 + t] = rsqrtf(var + 1e-5f);
    }
}

// ---------------------------------------------------------------------------
// Kernel G (FROZEN from R3)
// ---------------------------------------------------------------------------
__global__ __launch_bounds__(64) void kG(const float* __restrict__ l2,
                                         const float* __restrict__ stats,
                                         const float* __restrict__ gamma,
                                         const float* __restrict__ beta,
                                         float* __restrict__ out) {
    const int bi = blockIdx.x;
    const int i  = bi % 60;
    const int t  = threadIdx.x;

    float x = -3.0e38f;
    if (t < 60) {
        const float val = l2[(size_t)bi * 60 + t];
        const float y   = (val - stats[t]) * stats[64 + t] * gamma[t] + beta[t];
        const int  br   = (i < 36) ? (i / 12) : 3;
        const int  lo   = (br < 3) ? br * 12 : 36;
        const int  hi   = (br < 3) ? lo + 12 : 60;
        const bool valid = (t >= lo) && (t < hi);
        x = valid ? y : (y - 1e13f);
    }
    float mx = x;
    #pragma unroll
    for (int o = 32; o > 0; o >>= 1) mx = fmaxf(mx, __shfl_xor(mx, o));
    float e = 0.f;
    if (t < 60) e = __expf(x - mx);
    float sm = e;
    #pragma unroll
    for (int o = 32; o > 0; o >>= 1) sm += __shfl_xor(sm, o);
    if (t < 60) out[(size_t)bi * 60 + t] = e / sm;
}

// ---------------------------------------------------------------------------
extern "C" void kernel_launch(void* const* d_in, const int* in_sizes, int n_in,
                              void* d_out, int out_size, void* d_ws, size_t ws_size,
                              hipStream_t stream) {
    const float* seq   = (const float*)d_in[0];
    const float* w1    = (const float*)d_in[1];
    const float* w2    = (const float*)d_in[2];
    const float* w     = (const float*)d_in[3];
    const float* bmat  = (const float*)d_in[4];
    const float* v     = (const float*)d_in[5];
    const float* gamma = (const float*)d_in[6];
    const float* beta  = (const float*)d_in[7];
    float* out = (float*)d_out;
    float* ws  = (float*)d_ws;

    float* f1p    = ws;                  // 3,932,160
    float* f2p    = ws + 3932160;        // 1,966,080
    float* f2     = ws + 5898240;        //   122,880
    float* g1     = ws + 6021120;        //   122,880
    float* logits = ws + 6144000;        //    28,800
    float* l2     = ws + 6172800;        //    28,800
    float* stats  = ws + 6201600;        //       128

    // PROBE: kA twice (idempotent). kA_dur = total_R8 - total_R7.
    kA<<<1024, 256, 0, stream>>>(seq, w1, w2, f1p, f2p);
    kA<<<1024, 256, 0, stream>>>(seq, w1, w2, f1p, f2p);
    kR<<<512, 256, 0, stream>>>(f2p, f2);
    kC<<<240, 256, 0, stream>>>(f1p, w, g1);
    kD<<<480, 256, 0, stream>>>(g1, f2, bmat, logits);
    kE<<<480, 256, 0, stream>>>(v, logits, l2);
    kF<<<60, 64, 0, stream>>>(l2, stats);
    kG<<<480, 64, 0, stream>>>(l2, stats, gamma, beta, out);
}

// Round 9
// 131.066 us; speedup vs baseline: 2.0545x; 2.0545x over previous
//
#include <hip/hip_runtime.h>
#include <cstdint>
#include <cstddef>

// B=8, C=256, N=1024, T=60
// seq [B][C][N][T] fp32 (503 MB), out [B][T][T] fp32
//
// R9: kA FROZEN (measured ~89us ~ roofline via R8 probe). Tail restructured:
//   K1 = kR (512 blocks) + kC-Ksplit-x4 (960 blocks) in one launch, 23 waves/CU
//   kD absorbs g1 4-partial reduction. 6 launches total (was 7).
//
// ws layout (float offsets):
//   f1p : [8 cg][B][60][1024]                 -> 3,932,160  @ 0
//   f2p : [B][C][16 chunks][60]               -> 1,966,080  @ 3,932,160
//   f2  : [B][C][60]                          ->   122,880  @ 5,898,240
//   g1p : [4 ks][B][60][C] partials over n    ->   491,520  @ 6,021,120
//   logits: [B][60][60]                       ->    28,800  @ 6,512,640
//   l2  : [B][60][60]                         ->    28,800  @ 6,541,440
//   stats: mean[60]@+0, rstd[60]@+64          ->       128  @ 6,570,240

#define CSTRIDE 61440  // 1024*60 floats per c-plane

typedef float vfloat4 __attribute__((ext_vector_type(4)));

// quad-lane (xor1 + xor2) sum via DPP quad_perm — VALU only, no LDS pipe.
__device__ __forceinline__ float quad_reduce(float x) {
    int y1 = __builtin_amdgcn_update_dpp(0, __float_as_int(x), 0xB1, 0xF, 0xF, true);
    float s1 = x + __int_as_float(y1);
    int y2 = __builtin_amdgcn_update_dpp(0, __float_as_int(s1), 0x4E, 0xF, 0xF, true);
    return s1 + __int_as_float(y2);
}

// ---------------------------------------------------------------------------
// Kernel A (FROZEN from R7; ~89us, ~roofline): 4-deep NT pipeline; DPP f2
// reduce; LDS buffer; cross-wave reduce + flush to f2p [B][C][16][60].
// ---------------------------------------------------------------------------
__global__ __launch_bounds__(256) void kA(const float* __restrict__ seq,
                                          const float* __restrict__ w1,
                                          const float* __restrict__ w2,
                                          float* __restrict__ f1p,
                                          float* __restrict__ f2p) {
    const int blk  = blockIdx.x;            // 1024
    const int b    = blk >> 7;              // 0..7
    const int cg   = (blk >> 4) & 7;        // 0..7
    const int nc   = blk & 15;              // 0..15
    const int tid  = threadIdx.x;
    const int wv   = tid >> 6;              // 0..3
    const int lane = tid & 63;
    const int q    = lane & 3;              // n-sub
    const int r    = lane >> 2;             // t-quad; r==15 inactive
    const bool act = (r < 15);
    const int base_n = (nc << 6) + (wv << 4);
    const int c0   = cg << 5;

    __shared__ float lf2[7680];             // [cc 32][wv 4][60]

    float w2v[4];
    #pragma unroll
    for (int j = 0; j < 4; ++j) w2v[j] = w2[base_n + 4 * j + q];

    const size_t planeOff = (size_t)(b * 256 + c0) * CSTRIDE + (size_t)((base_n + q) * 60 + 4 * r);
    const float* p0 = seq + planeOff;
    const float* p1 = p0 + (size_t)CSTRIDE;
    const float* p2 = p0 + 2 * (size_t)CSTRIDE;
    const float* p3 = p0 + 3 * (size_t)CSTRIDE;

    vfloat4 P0[4], P1[4], P2[4], P3[4];
    #pragma unroll
    for (int j = 0; j < 4; ++j) {
        P0[j] = (vfloat4)(0.f);
        P1[j] = P0[j]; P2[j] = P0[j]; P3[j] = P0[j];
    }
    if (act) {
        #pragma unroll
        for (int j = 0; j < 4; ++j) P0[j] = __builtin_nontemporal_load((const vfloat4*)(p0 + j * 240));
        #pragma unroll
        for (int j = 0; j < 4; ++j) P1[j] = __builtin_nontemporal_load((const vfloat4*)(p1 + j * 240));
        #pragma unroll
        for (int j = 0; j < 4; ++j) P2[j] = __builtin_nontemporal_load((const vfloat4*)(p2 + j * 240));
        #pragma unroll
        for (int j = 0; j < 4; ++j) P3[j] = __builtin_nontemporal_load((const vfloat4*)(p3 + j * 240));
    }
    p0 += 4 * (size_t)CSTRIDE;
    p1 += 4 * (size_t)CSTRIDE;
    p2 += 4 * (size_t)CSTRIDE;
    p3 += 4 * (size_t)CSTRIDE;

    vfloat4 acc[4];
    #pragma unroll
    for (int j = 0; j < 4; ++j) acc[j] = (vfloat4)(0.f);

#define KA_STEP(P, S, PP)                                                               \
    {                                                                                   \
        const int cc = (ii << 2) + (S);                                                 \
        const float wc = w1[c0 + cc];                                                   \
        _Pragma("unroll")                                                               \
        for (int j = 0; j < 4; ++j) acc[j] += wc * P[j];                                \
        vfloat4 f2v = w2v[0]*P[0] + w2v[1]*P[1] + w2v[2]*P[2] + w2v[3]*P[3];            \
        if (pref) {                                                                     \
            _Pragma("unroll")                                                           \
            for (int j = 0; j < 4; ++j)                                                 \
                P[j] = __builtin_nontemporal_load((const vfloat4*)((PP) + j * 240));    \
        }                                                                               \
        f2v.x = quad_reduce(f2v.x);                                                     \
        f2v.y = quad_reduce(f2v.y);                                                     \
        f2v.z = quad_reduce(f2v.z);                                                     \
        f2v.w = quad_reduce(f2v.w);                                                     \
        if (act && q == 0) {                                                            \
            *(vfloat4*)(&lf2[(cc * 4 + wv) * 60 + 4 * r]) = f2v;                        \
        }                                                                               \
    }

    for (int ii = 0; ii < 8; ++ii) {
        const bool pref = act && (ii < 7);
        KA_STEP(P0, 0, p0)
        KA_STEP(P1, 1, p1)
        KA_STEP(P2, 2, p2)
        KA_STEP(P3, 3, p3)
        p0 += 4 * (size_t)CSTRIDE;
        p1 += 4 * (size_t)CSTRIDE;
        p2 += 4 * (size_t)CSTRIDE;
        p3 += 4 * (size_t)CSTRIDE;
    }
#undef KA_STEP

    if (act) {
        float* dst = f1p + ((size_t)((cg * 8 + b) * 60 + 4 * r)) * 1024 + base_n + q;
        #pragma unroll
        for (int j = 0; j < 4; ++j) {
            dst[0 * 1024 + 4 * j] = acc[j].x;
            dst[1 * 1024 + 4 * j] = acc[j].y;
            dst[2 * 1024 + 4 * j] = acc[j].z;
            dst[3 * 1024 + 4 * j] = acc[j].w;
        }
    }

    __syncthreads();
    #pragma unroll
    for (int k = 0; k < 2; ++k) {
        const int id4 = tid + k * 256;
        if (id4 < 480) {
            const int cc = id4 / 15;
            const int p  = id4 - cc * 15;
            vfloat4 s = (vfloat4)(0.f);
            #pragma unroll
            for (int w = 0; w < 4; ++w)
                s += *(const vfloat4*)(&lf2[(cc * 4 + w) * 60 + 4 * p]);
            *(vfloat4*)(f2p + ((size_t)(b * 256 + c0 + cc) * 16 + nc) * 60 + 4 * p) = s;
        }
    }
}

// ---------------------------------------------------------------------------
// K1: split grid.
//  blocks [0,512): f2 = sum of 16 nc chunks (4 rows/block).         [was kR]
//  blocks [512,1472): 960 = b(8) x tg(30) x ks(4): g1 partials over a
//    256-n slice. 2 t-rows staged (8 cg partials summed) in LDS.    [was kC]
// grid 1472 ~ 6 blocks/CU -> ~23 waves/CU for latency hiding.
// ---------------------------------------------------------------------------
__global__ __launch_bounds__(256) void K1(const float* __restrict__ f2p,
                                          const float* __restrict__ f1p,
                                          const float* __restrict__ w,
                                          float* __restrict__ f2,
                                          float* __restrict__ g1p) {
    const int blk = blockIdx.x;
    const int tid = threadIdx.x;
    if (blk < 512) {
        const int row = blk * 4 + (tid >> 6);   // (b*256+c)
        const int t   = tid & 63;
        if (t >= 60) return;
        const float* src = f2p + (size_t)row * 960 + t;
        float s = 0.f;
        #pragma unroll
        for (int k = 0; k < 16; ++k) s += src[k * 60];
        f2[(size_t)row * 60 + t] = s;
    } else {
        const int blk2 = blk - 512;             // 0..959
        const int b    = blk2 / 120;
        const int rem  = blk2 % 120;
        const int tg   = rem >> 2;              // 0..29
        const int ks   = rem & 3;               // 0..3
        const int c    = tid;

        __shared__ float fl[512];               // 2 rows x 256-n slice

        if (tid < 128) {
            const int row  = tid >> 6;
            const int col4 = tid & 63;
            const int t    = tg * 2 + row;
            vfloat4 s = (vfloat4)(0.f);
            #pragma unroll
            for (int g = 0; g < 8; ++g)
                s += *(const vfloat4*)(f1p + ((size_t)((g * 8 + b) * 60 + t)) * 1024
                                             + (ks << 8) + 4 * col4);
            *(vfloat4*)(&fl[(row << 8) + 4 * col4]) = s;
        }
        __syncthreads();

        float a0 = 0.f, a1 = 0.f;
        const float* wp = w + (size_t)(ks << 8) * 256 + c;
        #pragma unroll 4
        for (int n = 0; n < 256; ++n) {
            const float wv = wp[n * 256];
            a0 += fl[n] * wv;
            a1 += fl[256 + n] * wv;
        }
        float* dst = g1p + ((size_t)((ks * 8 + b) * 60 + tg * 2)) * 256 + c;
        dst[0]   = a0;
        dst[256] = a1;
    }
}

// ---------------------------------------------------------------------------
// Kernel D v2: absorbs g1 4-partial reduction during staging.
// logits[b,t,s] = sigmoid( sum_c g1[b,t,c]*f2[b,c,s] + bmat[t,s] ).
// grid 480 = b*60+t, block 256.
// ---------------------------------------------------------------------------
__global__ __launch_bounds__(256) void kD(const float* __restrict__ g1p,
                                          const float* __restrict__ f2,
                                          const float* __restrict__ bmat,
                                          float* __restrict__ logits) {
    const int bt = blockIdx.x;
    const int b  = bt / 60;
    const int t  = bt % 60;
    const int tid = threadIdx.x;
    const int cq = tid >> 6;
    const int s  = tid & 63;

    __shared__ float f2s[15364];
    __shared__ float g1r[256];
    __shared__ float red[256];

    const float* fsrc = f2 + (size_t)b * 15360;
    #pragma unroll
    for (int k = 0; k < 15; ++k) {
        const int idx = tid + k * 256;
        *(float4*)(&f2s[4 * idx]) = *(const float4*)(fsrc + 4 * idx);
    }
    if (tid < 64) {
        vfloat4 sg = (vfloat4)(0.f);
        #pragma unroll
        for (int ks = 0; ks < 4; ++ks)
            sg += *(const vfloat4*)(g1p + ((size_t)((ks * 8 + b) * 60 + t)) * 256 + 4 * tid);
        *(vfloat4*)(&g1r[4 * tid]) = sg;
    }
    __syncthreads();

    float acc = 0.f;
    #pragma unroll 8
    for (int cc = 0; cc < 64; ++cc) {
        const int c = cq * 64 + cc;
        acc += g1r[c] * f2s[c * 60 + s];
    }
    red[tid] = acc;
    __syncthreads();
    if (tid < 60) {
        const float x = red[tid] + red[64 + tid] + red[128 + tid] + red[192 + tid]
                      + bmat[t * 60 + tid];
        logits[(size_t)bt * 60 + tid] = 1.f / (1.f + __expf(-x));
    }
}

// ---------------------------------------------------------------------------
// Kernel E (FROZEN from R3)
// ---------------------------------------------------------------------------
__global__ __launch_bounds__(256) void kE(const float* __restrict__ v,
                                          const float* __restrict__ logits,
                                          float* __restrict__ l2) {
    const int bi = blockIdx.x;
    const int b  = bi / 60;
    const int i  = bi % 60;
    const int tid = threadIdx.x;

    __shared__ float L[3600];
    const float* src = logits + (size_t)b * 3600;
    #pragma unroll
    for (int k = 0; k < 3; ++k) {
        const int idx = tid + k * 256;
        *(float4*)(&L[4 * idx]) = *(const float4*)(src + 4 * idx);
    }
    if (tid < 132) {
        const int idx = tid + 768;
        *(float4*)(&L[4 * idx]) = *(const float4*)(src + 4 * idx);
    }
    __syncthreads();

    if (tid < 60) {
        float acc = 0.f;
        #pragma unroll 4
        for (int j = 0; j < 60; ++j) acc += v[i * 60 + j] * L[j * 60 + tid];
        l2[(size_t)bi * 60 + tid] = acc;
    }
}

// ---------------------------------------------------------------------------
// Kernel F (FROZEN from R3)
// ---------------------------------------------------------------------------
__global__ __launch_bounds__(64) void kF(const float* __restrict__ l2,
                                         float* __restrict__ stats) {
    const int t = blockIdx.x;
    const int k = threadIdx.x;
    float s = 0.f, ss = 0.f;
    #pragma unroll
    for (int m = 0; m < 8; ++m) {
        const int idx = k + 64 * m;
        if (idx < 480) {
            const float x = l2[(size_t)idx * 60 + t];
            s  += x;
            ss += x * x;
        }
    }
    #pragma unroll
    for (int o = 32; o > 0; o >>= 1) { s += __shfl_xor(s, o); ss += __shfl_xor(ss, o); }
    if (k == 0) {
        const float m   = s * (1.f / 480.f);
        const float var = ss * (1.f / 480.f) - m * m;
        stats[t]      = m;
        stats[64 + t] = rsqrtf(var + 1e-5f);
    }
}

// ---------------------------------------------------------------------------
// Kernel G (FROZEN from R3)
// ---------------------------------------------------------------------------
__global__ __launch_bounds__(64) void kG(const float* __restrict__ l2,
                                         const float* __restrict__ stats,
                                         const float* __restrict__ gamma,
                                         const float* __restrict__ beta,
                                         float* __restrict__ out) {
    const int bi = blockIdx.x;
    const int i  = bi % 60;
    const int t  = threadIdx.x;

    float x = -3.0e38f;
    if (t < 60) {
        const float val = l2[(size_t)bi * 60 + t];
        const float y   = (val - stats[t]) * stats[64 + t] * gamma[t] + beta[t];
        const int  br   = (i < 36) ? (i / 12) : 3;
        const int  lo   = (br < 3) ? br * 12 : 36;
        const int  hi   = (br < 3) ? lo + 12 : 60;
        const bool valid = (t >= lo) && (t < hi);
        x = valid ? y : (y - 1e13f);
    }
    float mx = x;
    #pragma unroll
    for (int o = 32; o > 0; o >>= 1) mx = fmaxf(mx, __shfl_xor(mx, o));
    float e = 0.f;
    if (t < 60) e = __expf(x - mx);
    float sm = e;
    #pragma unroll
    for (int o = 32; o > 0; o >>= 1) sm += __shfl_xor(sm, o);
    if (t < 60) out[(size_t)bi * 60 + t] = e / sm;
}

// ---------------------------------------------------------------------------
extern "C" void kernel_launch(void* const* d_in, const int* in_sizes, int n_in,
                              void* d_out, int out_size, void* d_ws, size_t ws_size,
                              hipStream_t stream) {
    const float* seq   = (const float*)d_in[0];
    const float* w1    = (const float*)d_in[1];
    const float* w2    = (const float*)d_in[2];
    const float* w     = (const float*)d_in[3];
    const float* bmat  = (const float*)d_in[4];
    const float* v     = (const float*)d_in[5];
    const float* gamma = (const float*)d_in[6];
    const float* beta  = (const float*)d_in[7];
    float* out = (float*)d_out;
    float* ws  = (float*)d_ws;

    float* f1p    = ws;                  // 3,932,160
    float* f2p    = ws + 3932160;        // 1,966,080
    float* f2     = ws + 5898240;        //   122,880
    float* g1p    = ws + 6021120;        //   491,520
    float* logits = ws + 6512640;        //    28,800
    float* l2     = ws + 6541440;        //    28,800
    float* stats  = ws + 6570240;        //       128

    kA<<<1024, 256, 0, stream>>>(seq, w1, w2, f1p, f2p);
    K1<<<1472, 256, 0, stream>>>(f2p, f1p, w, f2, g1p);
    kD<<<480, 256, 0, stream>>>(g1p, f2, bmat, logits);
    kE<<<480, 256, 0, stream>>>(v, logits, l2);
    kF<<<60, 64, 0, stream>>>(l2, stats);
    kG<<<480, 64, 0, stream>>>(l2, stats, gamma, beta, out);
}